// Round 1
// baseline (27132.761 us; speedup 1.0000x reference)
//
#include <hip/hip_runtime.h>
#include <math.h>

namespace {

constexpr int B = 16, CIN = 8, D = 16, H = 128, W = 128;
constexpr int COUT = 32;
constexpr int PD = 7, PH = 63, PW = 63;           // pooled dims
constexpr float INV_CNT = 1.0f / (float)(PD * PH * PW);  // 1/27783

// out[b] = sum_c bias[c]  (starting value; main kernel atomically adds the means)
__global__ void init_out_kernel(const float* __restrict__ bias, float* __restrict__ out) {
    int b = threadIdx.x;
    if (b < B) {
        float s = 0.f;
        #pragma unroll
        for (int c = 0; c < COUT; ++c) s += bias[c];
        out[b] = s;
    }
}

// One block per (b, pd, ph). Thread t: cout = t&31, w-group g = t>>5 covering
// pooled windows pw = g*8 .. g*8+7 (g==7 has 7 valid windows).
__global__ __launch_bounds__(256, 2) void conv_pool_sum_kernel(
    const float* __restrict__ x,
    const float* __restrict__ wgt,     // [COUT][CIN][3][3][3]
    const float* __restrict__ cbias,   // [COUT]
    float* __restrict__ out)           // [B]
{
    const int blk = blockIdx.x;
    const int ph = blk % PH;
    const int pd = (blk / PH) % PD;
    const int b  = blk / (PH * PD);

    const int t = threadIdx.x;
    const int c = t & 31;
    const int g = t >> 5;
    const int pw0 = g * 8;

    // acc[win][dd][hh][ww] : conv outputs for the 2x2x2 cells of 8 pooled windows
    float acc[8][2][2][2];
    #pragma unroll
    for (int i = 0; i < 8; ++i)
        #pragma unroll
        for (int j = 0; j < 2; ++j)
            #pragma unroll
            for (int k = 0; k < 2; ++k)
                #pragma unroll
                for (int l = 0; l < 2; ++l)
                    acc[i][j][k][l] = 0.f;

    const float* wb = wgt + c * (CIN * 27);
    const float* xb = x + (size_t)b * CIN * D * H * W;

    for (int ci = 0; ci < CIN; ++ci) {
        float wr[27];
        #pragma unroll
        for (int k = 0; k < 27; ++k) wr[k] = wb[ci * 27 + k];

        const float* xc = xb + (size_t)ci * (D * H * W);

        #pragma unroll
        for (int kd = 0; kd < 3; ++kd) {
            #pragma unroll
            for (int kh = 0; kh < 3; ++kh) {
                #pragma unroll
                for (int dd = 0; dd < 2; ++dd) {
                    #pragma unroll
                    for (int hh = 0; hh < 2; ++hh) {
                        // conv d = 2*pd+dd+kd (<=15), h = 2*ph+hh+kh (<=127)
                        const float* row = xc + (2 * pd + dd + kd) * (H * W)
                                              + (2 * ph + hh + kh) * W
                                              + pw0 * 2;           // 64B-aligned
                        float xr[18];
                        const float4* r4 = reinterpret_cast<const float4*>(row);
                        float4 v0 = r4[0], v1 = r4[1], v2 = r4[2], v3 = r4[3];
                        xr[0]  = v0.x; xr[1]  = v0.y; xr[2]  = v0.z; xr[3]  = v0.w;
                        xr[4]  = v1.x; xr[5]  = v1.y; xr[6]  = v1.z; xr[7]  = v1.w;
                        xr[8]  = v2.x; xr[9]  = v2.y; xr[10] = v2.z; xr[11] = v2.w;
                        xr[12] = v3.x; xr[13] = v3.y; xr[14] = v3.z; xr[15] = v3.w;
                        if (g < 7) { xr[16] = row[16]; xr[17] = row[17]; }
                        else       { xr[16] = 0.f;     xr[17] = 0.f;     }

                        const int wkb = (kd * 3 + kh) * 3;
                        #pragma unroll
                        for (int win = 0; win < 8; ++win)
                            #pragma unroll
                            for (int ww = 0; ww < 2; ++ww)
                                #pragma unroll
                                for (int kw = 0; kw < 3; ++kw)
                                    acc[win][dd][hh][ww] =
                                        fmaf(xr[2 * win + ww + kw], wr[wkb + kw],
                                             acc[win][dd][hh][ww]);
                    }
                }
            }
        }
    }

    // epilogue: +conv_bias, /2, max over 2x2x2, accumulate valid windows
    const float cb = cbias[c];
    float lsum = 0.f;
    #pragma unroll
    for (int win = 0; win < 8; ++win) {
        float m = -INFINITY;
        #pragma unroll
        for (int dd = 0; dd < 2; ++dd)
            #pragma unroll
            for (int hh = 0; hh < 2; ++hh)
                #pragma unroll
                for (int ww = 0; ww < 2; ++ww)
                    m = fmaxf(m, (acc[win][dd][hh][ww] + cb) * 0.5f);
        if (pw0 + win < PW) lsum += m;
    }

    // block reduction -> single atomic per block
    __shared__ float red[256];
    red[t] = lsum;
    __syncthreads();
    #pragma unroll
    for (int s = 128; s > 0; s >>= 1) {
        if (t < s) red[t] += red[t + s];
        __syncthreads();
    }
    if (t == 0) atomicAdd(&out[b], red[0] * INV_CNT);
}

} // namespace

extern "C" void kernel_launch(void* const* d_in, const int* in_sizes, int n_in,
                              void* d_out, int out_size, void* d_ws, size_t ws_size,
                              hipStream_t stream) {
    const float* x     = (const float*)d_in[0];
    const float* wgt   = (const float*)d_in[1];
    const float* cbias = (const float*)d_in[2];
    const float* bias  = (const float*)d_in[3];
    float* out = (float*)d_out;

    hipLaunchKernelGGL(init_out_kernel, dim3(1), dim3(64), 0, stream, bias, out);
    hipLaunchKernelGGL(conv_pool_sum_kernel, dim3(B * PD * PH), dim3(256), 0, stream,
                       x, wgt, cbias, out);
}

// Round 2
// 15748.749 us; speedup vs baseline: 1.7229x; 1.7229x over previous
//
#include <hip/hip_runtime.h>
#include <math.h>

namespace {

constexpr int B = 16, CIN = 8, D = 16, H = 128, W = 128;
constexpr int COUT = 32;
constexpr int PD = 7, PH = 63, PW = 63;           // pooled dims
constexpr float INV_CNT = 1.0f / (float)(PD * PH * PW);  // 1/27783

// out[b] = sum_c bias[c]  (starting value; main kernel atomically adds the means)
__global__ void init_out_kernel(const float* __restrict__ bias, float* __restrict__ out) {
    int b = threadIdx.x;
    if (b < B) {
        float s = 0.f;
        #pragma unroll
        for (int c = 0; c < COUT; ++c) s += bias[c];
        out[b] = s;
    }
}

// Grid: B * PD * PH * 2 tiles. Block covers a 32-pooled-window pw tile.
// Thread t: cout = t&31, group g = t>>5 handles windows pw0 = tile*32 + g*4 .. +3.
// Per-thread regs: acc 32 + wr 27 + xr 10 + addr ~20 ≈ 92  -> fits 128 cap, no spill.
__global__ __launch_bounds__(256, 4) void conv_pool_sum_kernel(
    const float* __restrict__ x,
    const float* __restrict__ wgt,     // [COUT][CIN][3][3][3]
    const float* __restrict__ cbias,   // [COUT]
    float* __restrict__ out)           // [B]
{
    const int blk  = blockIdx.x;
    const int tile = blk & 1;
    const int r    = blk >> 1;
    const int ph   = r % PH;
    const int pd   = (r / PH) % PD;
    const int b    = r / (PH * PD);

    const int t   = threadIdx.x;
    const int c   = t & 31;
    const int g   = t >> 5;
    const int pw0 = tile * 32 + g * 4;
    const bool tail = (pw0 + 3 >= PW);   // only pw0==60: window 63 invalid, don't read w>=128

    float acc[4][2][2][2];
    #pragma unroll
    for (int i = 0; i < 4; ++i)
        #pragma unroll
        for (int j = 0; j < 2; ++j)
            #pragma unroll
            for (int k = 0; k < 2; ++k)
                #pragma unroll
                for (int l = 0; l < 2; ++l)
                    acc[i][j][k][l] = 0.f;

    const float* wb = wgt + c * (CIN * 27);
    const float* xb = x + (size_t)b * CIN * D * H * W;

    for (int ci = 0; ci < CIN; ++ci) {
        float wr[27];
        #pragma unroll
        for (int k = 0; k < 27; ++k) wr[k] = wb[ci * 27 + k];

        const float* xc = xb + (size_t)ci * (D * H * W);

        #pragma unroll
        for (int kd = 0; kd < 3; ++kd) {
            #pragma unroll
            for (int kh = 0; kh < 3; ++kh) {
                #pragma unroll
                for (int dd = 0; dd < 2; ++dd) {
                    #pragma unroll
                    for (int hh = 0; hh < 2; ++hh) {
                        // conv d = 2*pd+dd+kd (<=15), h = 2*ph+hh+kh (<=127)
                        const float* row = xc + (2 * pd + dd + kd) * (H * W)
                                              + (2 * ph + hh + kh) * W
                                              + 2 * pw0;          // 32B-aligned
                        float xr[10];
                        const float4 v0 = *reinterpret_cast<const float4*>(row);
                        const float4 v1 = *reinterpret_cast<const float4*>(row + 4);
                        xr[0] = v0.x; xr[1] = v0.y; xr[2] = v0.z; xr[3] = v0.w;
                        xr[4] = v1.x; xr[5] = v1.y; xr[6] = v1.z; xr[7] = v1.w;
                        if (!tail) {
                            const float2 v2 = *reinterpret_cast<const float2*>(row + 8);
                            xr[8] = v2.x; xr[9] = v2.y;
                        } else {
                            xr[8] = 0.f; xr[9] = 0.f;
                        }

                        const int wk = (kd * 3 + kh) * 3;
                        #pragma unroll
                        for (int win = 0; win < 4; ++win)
                            #pragma unroll
                            for (int ww = 0; ww < 2; ++ww)
                                #pragma unroll
                                for (int kw = 0; kw < 3; ++kw)
                                    acc[win][dd][hh][ww] =
                                        fmaf(xr[2 * win + ww + kw], wr[wk + kw],
                                             acc[win][dd][hh][ww]);
                    }
                }
            }
        }
    }

    // epilogue: +conv_bias, /2, max over 2x2x2, accumulate valid windows
    const float cb = cbias[c];
    float lsum = 0.f;
    #pragma unroll
    for (int win = 0; win < 4; ++win) {
        float m = -INFINITY;
        #pragma unroll
        for (int dd = 0; dd < 2; ++dd)
            #pragma unroll
            for (int hh = 0; hh < 2; ++hh)
                #pragma unroll
                for (int ww = 0; ww < 2; ++ww)
                    m = fmaxf(m, (acc[win][dd][hh][ww] + cb) * 0.5f);
        if (pw0 + win < PW) lsum += m;
    }

    // block reduction -> single atomic per block
    __shared__ float red[256];
    red[t] = lsum;
    __syncthreads();
    #pragma unroll
    for (int s = 128; s > 0; s >>= 1) {
        if (t < s) red[t] += red[t + s];
        __syncthreads();
    }
    if (t == 0) atomicAdd(&out[b], red[0] * INV_CNT);
}

} // namespace

extern "C" void kernel_launch(void* const* d_in, const int* in_sizes, int n_in,
                              void* d_out, int out_size, void* d_ws, size_t ws_size,
                              hipStream_t stream) {
    const float* x     = (const float*)d_in[0];
    const float* wgt   = (const float*)d_in[1];
    const float* cbias = (const float*)d_in[2];
    const float* bias  = (const float*)d_in[3];
    float* out = (float*)d_out;

    hipLaunchKernelGGL(init_out_kernel, dim3(1), dim3(64), 0, stream, bias, out);
    hipLaunchKernelGGL(conv_pool_sum_kernel, dim3(B * PD * PH * 2), dim3(256), 0, stream,
                       x, wgt, cbias, out);
}

// Round 3
// 1123.272 us; speedup vs baseline: 24.1551x; 14.0204x over previous
//
#include <hip/hip_runtime.h>
#include <math.h>

namespace {

constexpr int B = 16, CIN = 8, D = 16, H = 128, W = 128;
constexpr int COUT = 32;
constexpr int PD = 7, PH = 63, PW = 63;           // pooled dims
constexpr float INV_CNT = 1.0f / (float)(PD * PH * PW);  // 1/27783

// out[b] = sum_c bias[c]  (starting value; main kernel atomically adds the means)
__global__ void init_out_kernel(const float* __restrict__ bias, float* __restrict__ out) {
    int b = threadIdx.x;
    if (b < B) {
        float s = 0.f;
        #pragma unroll
        for (int c = 0; c < COUT; ++c) s += bias[c];
        out[b] = s;
    }
}

// Grid: B * PD * PH * 2 tiles. Block covers a 32-pooled-window pw tile.
// Thread t: cout = t&31, group g = t>>5 handles windows pw0 = tile*32 + g*4 .. +3.
// Register budget note: usable arch-VGPRs = launch_bounds cap / 2 (observed
// r1: cap256->128, r2: cap128->64 — unified file split). So bounds (256,2)
// gives ~128 usable; live state acc32+wr27+xr10 ~= 69 fits.
__global__ __launch_bounds__(256, 2) void conv_pool_sum_kernel(
    const float* __restrict__ x,
    const float* __restrict__ wgt,     // [COUT][CIN][3][3][3]
    const float* __restrict__ cbias,   // [COUT]
    float* __restrict__ out)           // [B]
{
    const int blk  = blockIdx.x;
    const int tile = blk & 1;
    const int r    = blk >> 1;
    const int ph   = r % PH;
    const int pd   = (r / PH) % PD;
    const int b    = r / (PH * PD);

    const int t   = threadIdx.x;
    const int c   = t & 31;
    const int g   = t >> 5;
    const int pw0 = tile * 32 + g * 4;
    // Only pw0==60 would read w=128,129 (OOB). Address-select re-reads row+0
    // instead; garbage flows only into window 63's acc, which is masked below.
    const int tail_off = (pw0 + 3 >= PW) ? 0 : 8;

    float acc[4][2][2][2];
    #pragma unroll
    for (int i = 0; i < 4; ++i)
        #pragma unroll
        for (int j = 0; j < 2; ++j)
            #pragma unroll
            for (int k = 0; k < 2; ++k)
                #pragma unroll
                for (int l = 0; l < 2; ++l)
                    acc[i][j][k][l] = 0.f;

    const float* wb = wgt + c * (CIN * 27);
    const float* xb = x + (size_t)b * CIN * D * H * W + 2 * pw0;

    #pragma unroll 1
    for (int ci = 0; ci < CIN; ++ci) {
        float wr[27];
        #pragma unroll
        for (int k = 0; k < 27; ++k) wr[k] = wb[ci * 27 + k];

        const float* xc = xb + (size_t)ci * (D * H * W);

        #pragma unroll
        for (int kd = 0; kd < 3; ++kd) {
            #pragma unroll
            for (int kh = 0; kh < 3; ++kh) {
                #pragma unroll
                for (int dd = 0; dd < 2; ++dd) {
                    #pragma unroll
                    for (int hh = 0; hh < 2; ++hh) {
                        // conv d = 2*pd+dd+kd (<=15), h = 2*ph+hh+kh (<=127)
                        const float* row = xc + (2 * pd + dd + kd) * (H * W)
                                              + (2 * ph + hh + kh) * W;
                        float xr[10];
                        const float4 v0 = *reinterpret_cast<const float4*>(row);
                        const float4 v1 = *reinterpret_cast<const float4*>(row + 4);
                        const float2 v2 = *reinterpret_cast<const float2*>(row + tail_off);
                        xr[0] = v0.x; xr[1] = v0.y; xr[2] = v0.z; xr[3] = v0.w;
                        xr[4] = v1.x; xr[5] = v1.y; xr[6] = v1.z; xr[7] = v1.w;
                        xr[8] = v2.x; xr[9] = v2.y;

                        const int wk = (kd * 3 + kh) * 3;
                        #pragma unroll
                        for (int win = 0; win < 4; ++win)
                            #pragma unroll
                            for (int ww = 0; ww < 2; ++ww)
                                #pragma unroll
                                for (int kw = 0; kw < 3; ++kw)
                                    acc[win][dd][hh][ww] =
                                        fmaf(xr[2 * win + ww + kw], wr[wk + kw],
                                             acc[win][dd][hh][ww]);
                    }
                }
            }
        }
    }

    // epilogue: +conv_bias, /2, max over 2x2x2, accumulate valid windows
    const float cb = cbias[c];
    float lsum = 0.f;
    #pragma unroll
    for (int win = 0; win < 4; ++win) {
        float m = -INFINITY;
        #pragma unroll
        for (int dd = 0; dd < 2; ++dd)
            #pragma unroll
            for (int hh = 0; hh < 2; ++hh)
                #pragma unroll
                for (int ww = 0; ww < 2; ++ww)
                    m = fmaxf(m, (acc[win][dd][hh][ww] + cb) * 0.5f);
        if (pw0 + win < PW) lsum += m;
    }

    // block reduction -> single atomic per block
    __shared__ float red[256];
    red[t] = lsum;
    __syncthreads();
    #pragma unroll
    for (int s = 128; s > 0; s >>= 1) {
        if (t < s) red[t] += red[t + s];
        __syncthreads();
    }
    if (t == 0) atomicAdd(&out[b], red[0] * INV_CNT);
}

} // namespace

extern "C" void kernel_launch(void* const* d_in, const int* in_sizes, int n_in,
                              void* d_out, int out_size, void* d_ws, size_t ws_size,
                              hipStream_t stream) {
    const float* x     = (const float*)d_in[0];
    const float* wgt   = (const float*)d_in[1];
    const float* cbias = (const float*)d_in[2];
    const float* bias  = (const float*)d_in[3];
    float* out = (float*)d_out;

    hipLaunchKernelGGL(init_out_kernel, dim3(1), dim3(64), 0, stream, bias, out);
    hipLaunchKernelGGL(conv_pool_sum_kernel, dim3(B * PD * PH * 2), dim3(256), 0, stream,
                       x, wgt, cbias, out);
}

// Round 4
// 287.183 us; speedup vs baseline: 94.4789x; 3.9113x over previous
//
#include <hip/hip_runtime.h>
#include <math.h>

namespace {

constexpr int B = 16, CIN = 8, D = 16, H = 128, W = 128;
constexpr int COUT = 32;
constexpr int PD = 7, PH = 63, PW = 63;
constexpr float INV_CNT = 1.0f / (float)(PD * PH * PW);  // 1/27783
constexpr int DHW = D * H * W;

typedef short v8s __attribute__((ext_vector_type(8)));    // 8 bf16 (4 VGPR)
typedef float v16f __attribute__((ext_vector_type(16)));  // 32x32 acc

// LDS map:
//  tile: [d(4)][h(4)][w(128)][ci(8)] bf16; byte = ((d*4+h)*128+w)*16 ^ ((h&1)<<6); 32 KB
//  WB:   [pair(14)][lane(64)][ci(8)] bf16 at +32768; 14336 B
//  red:  8 floats at +47104
constexpr int WB_OFF = 32768, RED_OFF = 47104, LDS_BYTES = RED_OFF + 64;

__device__ inline unsigned short f2bf(float f) {          // RTN-even fp32->bf16
    unsigned int x = __builtin_bit_cast(unsigned int, f);
    return (unsigned short)((x + 0x7FFFu + ((x >> 16) & 1u)) >> 16);
}

__global__ void init_out_kernel(const float* __restrict__ bias, float* __restrict__ out) {
    int b = threadIdx.x;
    if (b < B) {
        float s = 0.f;
        #pragma unroll
        for (int c = 0; c < COUT; ++c) s += bias[c];
        out[b] = s;
    }
}

// One block per (b,pd,ph). 512 thr = 8 waves; wave wv covers pooled-w 8wv..8wv+7.
// Implicit GEMM, mfma_32x32x16_bf16: C[pos(32), cout(32)]; pos r = hh*16+pwl*2+ww.
// K = 216 taps (pad 224) as 14 pairs; k-slice of 8 = one tap x ci0..7 = 1 ds_read_b128.
__global__ __launch_bounds__(512, 2) void conv_mfma_kernel(
    const float* __restrict__ x,
    const float* __restrict__ wgt,     // [COUT][CIN][3][3][3]
    const float* __restrict__ cbias,
    float* __restrict__ out)
{
    __shared__ __align__(16) char smem[LDS_BYTES];

    // XCD swizzle: 7056 = 8 * 882 exact -> each XCD gets contiguous (b,pd,ph) run
    const int bid = blockIdx.x;
    const int logical = (bid & 7) * 882 + (bid >> 3);
    const int ph = logical % 63;
    const int pd = (logical / 63) % 7;
    const int b  = logical / 441;

    const int t    = threadIdx.x;
    const int lane = t & 63;
    const int wv   = t >> 6;

    // ---- stage WB: lane l of pair p needs W[cout=l&31][ci=0..7][tap=2p+(l>>5)] ----
    for (int pr = t; pr < 14 * 64; pr += 512) {
        const int p = pr >> 6, l = pr & 63;
        const int tap = 2 * p + (l >> 5);
        const int cout = l & 31;
        uint4 pk = {0u, 0u, 0u, 0u};
        if (tap < 27) {
            unsigned int v[4];
            #pragma unroll
            for (int j = 0; j < 4; ++j) {
                unsigned short b0 = f2bf(wgt[(cout * CIN + 2 * j) * 27 + tap]);
                unsigned short b1 = f2bf(wgt[(cout * CIN + 2 * j + 1) * 27 + tap]);
                v[j] = (unsigned int)b0 | ((unsigned int)b1 << 16);
            }
            pk.x = v[0]; pk.y = v[1]; pk.z = v[2]; pk.w = v[3];
        }
        *reinterpret_cast<uint4*>(smem + WB_OFF + pr * 16) = pk;
    }

    // ---- stage x tile: 2048 sites (d,h,w), 8 ci each -> bf16x8, ci innermost ----
    const float* xb = x + (size_t)b * CIN * DHW;
    for (int s = t; s < 2048; s += 512) {
        const int d = s >> 9, h = (s >> 7) & 3, w = s & 127;
        const float* xp = xb + (2 * pd + d) * (H * W) + (2 * ph + h) * W + w;
        unsigned int v[4];
        #pragma unroll
        for (int j = 0; j < 4; ++j) {
            unsigned short b0 = f2bf(xp[(2 * j) * DHW]);
            unsigned short b1 = f2bf(xp[(2 * j + 1) * DHW]);
            v[j] = (unsigned int)b0 | ((unsigned int)b1 << 16);
        }
        const int byte = (((d * 4 + h) * 128 + w) * 16) ^ ((h & 1) << 6);
        *reinterpret_cast<uint4*>(smem + byte) = uint4{v[0], v[1], v[2], v[3]};
    }

    __syncthreads();

    // ---- K loop: 14 pairs; A row r=lane&31 -> (hh,pwl,ww); half -> which tap of pair
    const int r    = lane & 31;
    const int half = lane >> 5;
    const int hh   = r >> 4;
    const int pwl  = (r >> 1) & 7;
    const int ww   = r & 1;
    const int wbase = 2 * (8 * wv + pwl) + ww;

    v16f acc0, acc1;
    #pragma unroll
    for (int i = 0; i < 16; ++i) { acc0[i] = 0.f; acc1[i] = 0.f; }

    #pragma unroll
    for (int ks = 0; ks < 14; ++ks) {
        const int t0 = 2 * ks, t1 = t0 + 1;
        const int KD0 = t0 / 9, KH0 = (t0 % 9) / 3, KW0 = t0 % 3;
        const int KD1 = (t1 < 27) ? t1 / 9 : 0;
        const int KH1 = (t1 < 27) ? (t1 % 9) / 3 : 0;
        const int KW1 = (t1 < 27) ? t1 % 3 : 0;
        const int kd = half ? KD1 : KD0;
        const int kh = half ? KH1 : KH0;
        const int kw = half ? KW1 : KW0;
        const int h = hh + kh;
        int w = wbase + kw; w = (w > 127) ? 127 : w;   // clamp: only pw=63 rows (masked)
        const int byte = (((kd * 4 + h) * 128 + w) * 16) ^ ((h & 1) << 6);

        const v8s A0 = *reinterpret_cast<const v8s*>(smem + byte);           // dd=0
        const v8s A1 = *reinterpret_cast<const v8s*>(smem + byte + 8192);    // dd=1
        const v8s Bf = *reinterpret_cast<const v8s*>(smem + WB_OFF + (ks * 64 + lane) * 16);
        acc0 = __builtin_amdgcn_mfma_f32_32x32x16_bf16(A0, Bf, acc0, 0, 0, 0);
        acc1 = __builtin_amdgcn_mfma_f32_32x32x16_bf16(A1, Bf, acc1, 0, 0, 0);
    }

    // ---- epilogue: C row=(reg&3)+8*(reg>>2)+4*half, col=lane&31=cout ----
    // window j regs: {2j, 2j+1, 8+2j, 9+2j} in both accs; pwl = (j&1)+((j>>1)<<2)+2*half
    const float cb = cbias[lane & 31];
    float lsum = 0.f;
    #pragma unroll
    for (int j = 0; j < 4; ++j) {
        float m = fmaxf(fmaxf(acc0[2 * j], acc0[2 * j + 1]),
                        fmaxf(acc0[8 + 2 * j], acc0[9 + 2 * j]));
        m = fmaxf(m, fmaxf(fmaxf(acc1[2 * j], acc1[2 * j + 1]),
                           fmaxf(acc1[8 + 2 * j], acc1[9 + 2 * j])));
        const int pw = 8 * wv + ((j & 1) + ((j >> 1) << 2) + 2 * half);
        if (pw < PW) lsum += (m + cb) * 0.5f;
    }

    #pragma unroll
    for (int o = 32; o > 0; o >>= 1) lsum += __shfl_xor(lsum, o, 64);
    if (lane == 0) *reinterpret_cast<float*>(smem + RED_OFF + wv * 4) = lsum;
    __syncthreads();
    if (t == 0) {
        float s = 0.f;
        #pragma unroll
        for (int i = 0; i < 8; ++i) s += reinterpret_cast<float*>(smem + RED_OFF)[i];
        atomicAdd(&out[b], s * INV_CNT);
    }
}

} // namespace

extern "C" void kernel_launch(void* const* d_in, const int* in_sizes, int n_in,
                              void* d_out, int out_size, void* d_ws, size_t ws_size,
                              hipStream_t stream) {
    const float* x     = (const float*)d_in[0];
    const float* wgt   = (const float*)d_in[1];
    const float* cbias = (const float*)d_in[2];
    const float* bias  = (const float*)d_in[3];
    float* out = (float*)d_out;

    hipLaunchKernelGGL(init_out_kernel, dim3(1), dim3(64), 0, stream, bias, out);
    hipLaunchKernelGGL(conv_mfma_kernel, dim3(B * PD * PH), dim3(512), 0, stream,
                       x, wgt, cbias, out);
}

// Round 5
// 242.851 us; speedup vs baseline: 111.7261x; 1.1826x over previous
//
#include <hip/hip_runtime.h>
#include <math.h>

namespace {

constexpr int B = 16, CIN = 8, D = 16, H = 128, W = 128;
constexpr int PW = 63;
constexpr float INV_CNT = 1.0f / 27783.0f;   // 1/(7*63*63)
constexpr int HW = H * W, DHW = D * HW;

typedef short v8s  __attribute__((ext_vector_type(8)));   // 8 bf16
typedef float v16f __attribute__((ext_vector_type(16)));  // 32x32 acc

// LDS: tile [d16][h4][w128][ci8] bf16, byte = site*16 ^ ((h&1)<<6)  -> 131072 B
//      WB [pair14][lane64][ci8] bf16 at +131072                     ->  14336 B
//      red: 8 floats                                                ->     64 B
constexpr int WB_OFF = 131072;
constexpr int RED_OFF = WB_OFF + 14336;
constexpr int LDS_BYTES = RED_OFF + 64;      // 145472 < 160 KiB -> 1 block/CU

__device__ inline unsigned short f2bf(float f) {          // RTN-even fp32->bf16
    unsigned int x = __builtin_bit_cast(unsigned int, f);
    return (unsigned short)((x + 0x7FFFu + ((x >> 16) & 1u)) >> 16);
}

// One block per (b, ph): stage full-D slab once, loop pd=0..6 over it.
// 8 waves; wave wv covers pooled-w 8wv..8wv+7. mfma_32x32x16_bf16,
// C[pos32, cout32]; A row r: hh=r>>4, pwl=(r>>1)&7, ww=r&1; K=2 taps x 8 ci.
__global__ __launch_bounds__(512, 2) void conv_mfma_kernel(
    const float* __restrict__ x,
    const float* __restrict__ wgt,      // [32][8][3][3][3]
    const float* __restrict__ cbias,    // [32]
    float* __restrict__ partials)       // [1008]
{
    __shared__ __align__(16) char smem[LDS_BYTES];

    const int bid = blockIdx.x;                    // 1008 = 8 * 126 exact
    const int logical = (bid & 7) * 126 + (bid >> 3);
    const int ph = logical % 63;
    const int b  = logical / 63;

    const int t = threadIdx.x, lane = t & 63, wv = t >> 6;

    // ---- stage WB: lane l of pair p = W[cout=l&31][ci 0..7][tap=2p+(l>>5)] ----
    for (int pr = t; pr < 14 * 64; pr += 512) {
        const int p = pr >> 6, l = pr & 63;
        const int tap = 2 * p + (l >> 5), cout = l & 31;
        uint4 pk = {0u, 0u, 0u, 0u};
        if (tap < 27) {
            unsigned int v[4];
            #pragma unroll
            for (int j = 0; j < 4; ++j) {
                unsigned short b0 = f2bf(wgt[(cout * CIN + 2 * j) * 27 + tap]);
                unsigned short b1 = f2bf(wgt[(cout * CIN + 2 * j + 1) * 27 + tap]);
                v[j] = (unsigned int)b0 | ((unsigned int)b1 << 16);
            }
            pk = uint4{v[0], v[1], v[2], v[3]};
        }
        *reinterpret_cast<uint4*>(smem + WB_OFF + pr * 16) = pk;
    }

    // ---- stage x slab: 8192 sites (d 0..15, h 0..3, w 0..127), 8 ci each ----
    const float* xb = x + (size_t)b * CIN * DHW;
    #pragma unroll 4
    for (int s = t; s < 8192; s += 512) {
        const int d = s >> 9, h = (s >> 7) & 3, w = s & 127;
        const float* xp = xb + d * HW + (2 * ph + h) * W + w;
        unsigned int v[4];
        #pragma unroll
        for (int j = 0; j < 4; ++j) {
            unsigned short b0 = f2bf(xp[(2 * j) * DHW]);
            unsigned short b1 = f2bf(xp[(2 * j + 1) * DHW]);
            v[j] = (unsigned int)b0 | ((unsigned int)b1 << 16);
        }
        const int byte = (s * 16) ^ ((h & 1) << 6);     // s == (d*4+h)*128+w
        *reinterpret_cast<uint4*>(smem + byte) = uint4{v[0], v[1], v[2], v[3]};
    }

    __syncthreads();

    // ---- B fragments to registers (56 VGPR) ----
    v8s Bf[14];
    #pragma unroll
    for (int ks = 0; ks < 14; ++ks)
        Bf[ks] = *reinterpret_cast<const v8s*>(smem + WB_OFF + (ks * 64 + lane) * 16);

    const int r = lane & 31, half = lane >> 5;
    const int hh = r >> 4, pwl = (r >> 1) & 7, ww = r & 1;
    const int wbase = 2 * (8 * wv + pwl) + ww;

    // ---- per-lane A byte offsets at pd=0, dd=0 (static-indexed array) ----
    int offA[14];
    #pragma unroll
    for (int ks = 0; ks < 14; ++ks) {
        const int t0 = 2 * ks, t1 = t0 + 1;
        const int KD0 = t0 / 9, KH0 = (t0 % 9) / 3, KW0 = t0 % 3;
        const int KD1 = (t1 < 27) ? t1 / 9 : 0;
        const int KH1 = (t1 < 27) ? (t1 % 9) / 3 : 0;
        const int KW1 = (t1 < 27) ? t1 % 3 : 0;
        const int kd = half ? KD1 : KD0;
        const int kh = half ? KH1 : KH0;
        const int kw = half ? KW1 : KW0;
        const int h = hh + kh;
        int w = wbase + kw; w = (w > 127) ? 127 : w;   // clamp: only pw=63 (masked)
        offA[ks] = (((kd * 4 + h) * 128 + w) * 16) ^ ((h & 1) << 6);
    }

    const float cb = cbias[lane & 31];
    float lsum = 0.f;

    #pragma unroll 1
    for (int pd = 0; pd < 7; ++pd) {
        v16f acc0, acc1;
        #pragma unroll
        for (int i = 0; i < 16; ++i) { acc0[i] = 0.f; acc1[i] = 0.f; }
        const int pbase = pd * 16384;                  // +2 d-planes per pd

        #pragma unroll
        for (int ks = 0; ks < 14; ++ks) {
            const v8s A0 = *reinterpret_cast<const v8s*>(smem + pbase + offA[ks]);
            const v8s A1 = *reinterpret_cast<const v8s*>(smem + pbase + offA[ks] + 8192);
            acc0 = __builtin_amdgcn_mfma_f32_32x32x16_bf16(A0, Bf[ks], acc0, 0, 0, 0);
            acc1 = __builtin_amdgcn_mfma_f32_32x32x16_bf16(A1, Bf[ks], acc1, 0, 0, 0);
        }

        // C row=(reg&3)+8*(reg>>2)+4*half; window j regs {2j,2j+1,8+2j,9+2j}
        #pragma unroll
        for (int j = 0; j < 4; ++j) {
            float m = fmaxf(fmaxf(acc0[2 * j], acc0[2 * j + 1]),
                            fmaxf(acc0[8 + 2 * j], acc0[9 + 2 * j]));
            m = fmaxf(m, fmaxf(fmaxf(acc1[2 * j], acc1[2 * j + 1]),
                               fmaxf(acc1[8 + 2 * j], acc1[9 + 2 * j])));
            const int pw = 8 * wv + ((j & 1) + ((j >> 1) << 2) + 2 * half);
            if (pw < PW) lsum += (m + cb) * 0.5f;
        }
    }

    #pragma unroll
    for (int o = 32; o > 0; o >>= 1) lsum += __shfl_xor(lsum, o, 64);
    if (lane == 0) *reinterpret_cast<float*>(smem + RED_OFF + wv * 4) = lsum;
    __syncthreads();
    if (t == 0) {
        float s = 0.f;
        #pragma unroll
        for (int i = 0; i < 8; ++i) s += reinterpret_cast<float*>(smem + RED_OFF)[i];
        partials[logical] = s;                         // plain store, no atomics
    }
}

// out[b] = INV_CNT * sum_ph partials[b*63+ph] + sum_c bias[c]
__global__ void finalize_kernel(const float* __restrict__ partials,
                                const float* __restrict__ bias,
                                float* __restrict__ out)
{
    const int t = threadIdx.x;          // 512 = 16 b-groups x 32 lanes
    const int b = t >> 5, l = t & 31;
    float s = 0.f;
    for (int j = l; j < 63; j += 32) s += partials[b * 63 + j];
    s = s * INV_CNT + bias[l];
    #pragma unroll
    for (int o = 16; o > 0; o >>= 1) s += __shfl_xor(s, o, 32);
    if (l == 0) out[b] = s;
}

} // namespace

extern "C" void kernel_launch(void* const* d_in, const int* in_sizes, int n_in,
                              void* d_out, int out_size, void* d_ws, size_t ws_size,
                              hipStream_t stream) {
    const float* x     = (const float*)d_in[0];
    const float* wgt   = (const float*)d_in[1];
    const float* cbias = (const float*)d_in[2];
    const float* bias  = (const float*)d_in[3];
    float* out      = (float*)d_out;
    float* partials = (float*)d_ws;     // 1008 floats

    hipLaunchKernelGGL(conv_mfma_kernel, dim3(B * 63), dim3(512), 0, stream,
                       x, wgt, cbias, partials);
    hipLaunchKernelGGL(finalize_kernel, dim3(1), dim3(512), 0, stream,
                       partials, bias, out);
}